// Round 6
// baseline (210.102 us; speedup 1.0000x reference)
//
#include <hip/hip_runtime.h>
#include <math.h>

#define NROWS 8192
#define DDIM  128
#define BATCH 64

typedef float f4_t __attribute__((ext_vector_type(4)));

__device__ __forceinline__ void f4_add(f4_t& a, const f4_t b) { a += b; }
__device__ __forceinline__ void f4_fma_sq(f4_t& a, const f4_t b) {
    a.x = fmaf(b.x, b.x, a.x); a.y = fmaf(b.y, b.y, a.y);
    a.z = fmaf(b.z, b.z, a.z); a.w = fmaf(b.w, b.w, a.w);
}
__device__ __forceinline__ void f4_max(f4_t& a, const f4_t b) {
    a.x = fmaxf(a.x, b.x); a.y = fmaxf(a.y, b.y);
    a.z = fmaxf(a.z, b.z); a.w = fmaxf(a.w, b.w);
}
__device__ __forceinline__ void f4_min(f4_t& a, const f4_t b) {
    a.x = fminf(a.x, b.x); a.y = fminf(a.y, b.y);
    a.z = fminf(a.z, b.z); a.w = fminf(a.w, b.w);
}

// Fused: block (b, c) reduces rows {c + j*NCHUNK} of batch b (R3's proven
// row-interleaved pattern: half-wave 512B segments, dense per-batch sweep
// window). Last-arriving block of each batch combines the NCHUNK partials
// and writes the 5 outputs (threadfence-reduction pattern; slot order fixed
// -> deterministic).
// ws layout: float ws[B][NCHUNK][4][128] partials, then int ctr[B].
template <int NCHUNK>
__global__ __launch_bounds__(256) void agg_fused(const float* __restrict__ in,
                                                 float* __restrict__ ws,
                                                 float* __restrict__ out) {
    constexpr int ROWS = NROWS / NCHUNK;
    const int blk = blockIdx.x;
    const int b = blk / NCHUNK;
    const int c = blk % NCHUNK;
    const int tid = threadIdx.x;
    const int d4 = tid & 31;               // float4 column (d = 4*d4..4*d4+3)
    const int rg = tid >> 5;               // row group 0..7

    // row r(j) = c + j*NCHUNK, j = rg + 8*i  (R3 layout)
    const f4_t* __restrict__ base =
        (const f4_t*)(in + (size_t)b * NROWS * DDIM) +
        (size_t)(c + rg * NCHUNK) * (DDIM / 4) + d4;
    constexpr size_t ISTRIDE = (size_t)8 * NCHUNK * (DDIM / 4); // j += 8

    f4_t sum0 = (f4_t)0.f, sum1 = (f4_t)0.f;
    f4_t sq0  = (f4_t)0.f, sq1  = (f4_t)0.f;
    f4_t mx0  = (f4_t)(-INFINITY), mx1 = (f4_t)(-INFINITY);
    f4_t mn0  = (f4_t)( INFINITY), mn1 = (f4_t)( INFINITY);

    constexpr int ITERS = ROWS / 8;
#pragma unroll 8
    for (int i = 0; i < ITERS; i += 2) {
        f4_t v0 = __builtin_nontemporal_load(base + (size_t)i * ISTRIDE);
        f4_t v1 = __builtin_nontemporal_load(base + (size_t)(i + 1) * ISTRIDE);
        f4_add(sum0, v0); f4_fma_sq(sq0, v0); f4_max(mx0, v0); f4_min(mn0, v0);
        f4_add(sum1, v1); f4_fma_sq(sq1, v1); f4_max(mx1, v1); f4_min(mn1, v1);
    }
    f4_add(sum0, sum1);
    f4_add(sq0, sq1);
    f4_max(mx0, mx1);
    f4_min(mn0, mn1);

    __shared__ f4_t s_sum[256];
    __shared__ f4_t s_sq[256];
    __shared__ f4_t s_mx[256];
    __shared__ f4_t s_mn[256];
    s_sum[tid] = sum0; s_sq[tid] = sq0; s_mx[tid] = mx0; s_mn[tid] = mn0;
    __syncthreads();

    if (tid < 32) {
#pragma unroll
        for (int r = 1; r < 8; ++r) {
            const int i = r * 32 + tid;
            f4_add(sum0, s_sum[i]);
            f4_add(sq0,  s_sq[i]);
            f4_max(mx0,  s_mx[i]);
            f4_min(mn0,  s_mn[i]);
        }
        // nt store: memory-side (L3/HBM), so cross-XCD visibility needs no
        // L2 writeback on the release fence.
        float* wsb = ws + ((size_t)(b * NCHUNK + c) * 4) * DDIM;
        __builtin_nontemporal_store(sum0, (f4_t*)(wsb + 0 * DDIM) + tid);
        __builtin_nontemporal_store(sq0,  (f4_t*)(wsb + 1 * DDIM) + tid);
        __builtin_nontemporal_store(mx0,  (f4_t*)(wsb + 2 * DDIM) + tid);
        __builtin_nontemporal_store(mn0,  (f4_t*)(wsb + 3 * DDIM) + tid);
    }
    __syncthreads();

    int* ctr = (int*)(ws + (size_t)BATCH * NCHUNK * 4 * DDIM);
    __shared__ int s_old;
    if (tid == 0) {
        __threadfence();                   // release our partial stores
        s_old = atomicAdd(&ctr[b], 1);
    }
    __syncthreads();

    if (s_old == NCHUNK - 1) {
        __threadfence();                   // acquire: invalidate stale lines
        const int d = tid;
        if (d < DDIM) {
            const float* pb = ws + (size_t)b * NCHUNK * 4 * DDIM + d;
            float sum = 0.f, sq = 0.f;
            float mx = -INFINITY, mn = INFINITY;
#pragma unroll 4
            for (int c2 = 0; c2 < NCHUNK; ++c2) {
                const float* p = pb + (size_t)c2 * 4 * DDIM;
                sum += p[0 * DDIM];
                sq  += p[1 * DDIM];
                mx = fmaxf(mx, p[2 * DDIM]);
                mn = fminf(mn, p[3 * DDIM]);
            }
            const float inv_n = 1.f / (float)NROWS;
            const float mean = sum * inv_n;
            const float var = fmaxf(0.f, sq * inv_n - mean * mean);
            const float stdv = sqrtf(var);

            float* ob = out + (size_t)b * 5 * DDIM;
            ob[0 * DDIM + d] = mean;
            ob[1 * DDIM + d] = mx;
            ob[2 * DDIM + d] = mn;
            ob[3 * DDIM + d] = sum;
            ob[4 * DDIM + d] = stdv;
        }
    }
}

extern "C" void kernel_launch(void* const* d_in, const int* in_sizes, int n_in,
                              void* d_out, int out_size, void* d_ws, size_t ws_size,
                              hipStream_t stream) {
    const float* in = (const float*)d_in[0];
    float* out = (float*)d_out;
    float* ws = (float*)d_ws;

    // ws need: B*NCHUNK*4*128 floats + B ints.
    const size_t need32 = (size_t)BATCH * 32 * 4 * DDIM * sizeof(float) + BATCH * sizeof(int);
    const size_t need8  = (size_t)BATCH *  8 * 4 * DDIM * sizeof(float) + BATCH * sizeof(int);

    if (ws_size >= need32) {
        float* ctr = ws + (size_t)BATCH * 32 * 4 * DDIM;
        hipMemsetAsync((void*)ctr, 0, BATCH * sizeof(int), stream);
        agg_fused<32><<<BATCH * 32, 256, 0, stream>>>(in, ws, out);
    } else if (ws_size >= need8) {
        float* ctr = ws + (size_t)BATCH * 8 * 4 * DDIM;
        hipMemsetAsync((void*)ctr, 0, BATCH * sizeof(int), stream);
        agg_fused<8><<<BATCH * 8, 256, 0, stream>>>(in, ws, out);
    } else {
        float* ctr = ws + (size_t)BATCH * 1 * 4 * DDIM;
        hipMemsetAsync((void*)ctr, 0, BATCH * sizeof(int), stream);
        agg_fused<1><<<BATCH * 1, 256, 0, stream>>>(in, ws, out);
    }
}

// Round 7
// 51.587 us; speedup vs baseline: 4.0728x; 4.0728x over previous
//
#include <hip/hip_runtime.h>
#include <math.h>

#define NROWS 8192
#define DDIM  128
#define BATCH 64

typedef float f4_t __attribute__((ext_vector_type(4)));

__device__ __forceinline__ void f4_add(f4_t& a, const f4_t b) { a += b; }
__device__ __forceinline__ void f4_fma_sq(f4_t& a, const f4_t b) {
    a.x = fmaf(b.x, b.x, a.x); a.y = fmaf(b.y, b.y, a.y);
    a.z = fmaf(b.z, b.z, a.z); a.w = fmaf(b.w, b.w, a.w);
}
__device__ __forceinline__ void f4_max(f4_t& a, const f4_t b) {
    a.x = fmaxf(a.x, b.x); a.y = fmaxf(a.y, b.y);
    a.z = fmaxf(a.z, b.z); a.w = fmaxf(a.w, b.w);
}
__device__ __forceinline__ void f4_min(f4_t& a, const f4_t b) {
    a.x = fminf(a.x, b.x); a.y = fminf(a.y, b.y);
    a.z = fminf(a.z, b.z); a.w = fminf(a.w, b.w);
}

// Stage 1 (R3 proven config, 52.1us): block (b, c) reduces rows
// {c + j*NCHUNK : j=0..ROWS-1} of batch b — row-interleaved so the NCHUNK
// blocks of a batch sweep one dense window. NT loads on input.
// ws layout: float ws[B][NCHUNK][4][128]  (stat: 0=sum, 1=sumsq, 2=max, 3=min)
template <int NCHUNK>
__global__ __launch_bounds__(256) void agg_stage1(const float* __restrict__ in,
                                                  float* __restrict__ ws) {
    constexpr int ROWS = NROWS / NCHUNK;   // rows per block (256 for NCHUNK=32)
    const int blk = blockIdx.x;
    const int b = blk / NCHUNK;
    const int c = blk % NCHUNK;
    const int tid = threadIdx.x;
    const int d4 = tid & 31;               // float4 column (d = 4*d4..4*d4+3)
    const int rg = tid >> 5;               // row group 0..7

    // row r(j) = c + j*NCHUNK, j = rg + 8*i
    const f4_t* __restrict__ base =
        (const f4_t*)(in + (size_t)b * NROWS * DDIM) +
        (size_t)(c + rg * NCHUNK) * (DDIM / 4) + d4;
    constexpr size_t ISTRIDE = (size_t)8 * NCHUNK * (DDIM / 4); // j += 8

    f4_t sum0 = (f4_t)0.f, sum1 = (f4_t)0.f;
    f4_t sq0  = (f4_t)0.f, sq1  = (f4_t)0.f;
    f4_t mx0  = (f4_t)(-INFINITY), mx1 = (f4_t)(-INFINITY);
    f4_t mn0  = (f4_t)( INFINITY), mn1 = (f4_t)( INFINITY);

    constexpr int ITERS = ROWS / 8;        // 32 for NCHUNK=32
#pragma unroll 8
    for (int i = 0; i < ITERS; i += 2) {
        f4_t v0 = __builtin_nontemporal_load(base + (size_t)i * ISTRIDE);
        f4_t v1 = __builtin_nontemporal_load(base + (size_t)(i + 1) * ISTRIDE);
        f4_add(sum0, v0); f4_fma_sq(sq0, v0); f4_max(mx0, v0); f4_min(mn0, v0);
        f4_add(sum1, v1); f4_fma_sq(sq1, v1); f4_max(mx1, v1); f4_min(mn1, v1);
    }
    f4_add(sum0, sum1);
    f4_add(sq0, sq1);
    f4_max(mx0, mx1);
    f4_min(mn0, mn1);

    __shared__ f4_t s_sum[256];
    __shared__ f4_t s_sq[256];
    __shared__ f4_t s_mx[256];
    __shared__ f4_t s_mn[256];
    s_sum[tid] = sum0; s_sq[tid] = sq0; s_mx[tid] = mx0; s_mn[tid] = mn0;
    __syncthreads();

    if (tid < 32) {
#pragma unroll
        for (int r = 1; r < 8; ++r) {
            const int i = r * 32 + tid;
            f4_add(sum0, s_sum[i]);
            f4_add(sq0,  s_sq[i]);
            f4_max(mx0,  s_mx[i]);
            f4_min(mn0,  s_mn[i]);
        }
        float* wsb = ws + ((size_t)(b * NCHUNK + c) * 4) * DDIM;
        ((f4_t*)(wsb + 0 * DDIM))[tid] = sum0;
        ((f4_t*)(wsb + 1 * DDIM))[tid] = sq0;
        ((f4_t*)(wsb + 2 * DDIM))[tid] = mx0;
        ((f4_t*)(wsb + 3 * DDIM))[tid] = mn0;
    }
}

// Stage 2: one thread per (b, d); combine NCHUNK partials (fully unrolled),
// emit 5 outputs.
template <int NCHUNK>
__global__ __launch_bounds__(256) void agg_stage2(const float* __restrict__ ws,
                                                  float* __restrict__ out) {
    const int g = blockIdx.x * blockDim.x + threadIdx.x;
    if (g >= BATCH * DDIM) return;
    const int b = g >> 7;
    const int d = g & 127;

    float sum = 0.f, sq = 0.f;
    float mx = -INFINITY, mn = INFINITY;
    const float* pb = ws + (size_t)b * NCHUNK * 4 * DDIM + d;
#pragma unroll
    for (int c = 0; c < NCHUNK; ++c) {
        const float* p = pb + (size_t)c * 4 * DDIM;
        sum += p[0 * DDIM];
        sq  += p[1 * DDIM];
        mx = fmaxf(mx, p[2 * DDIM]);
        mn = fminf(mn, p[3 * DDIM]);
    }
    const float inv_n = 1.f / (float)NROWS;
    const float mean = sum * inv_n;
    const float var = fmaxf(0.f, sq * inv_n - mean * mean);
    const float stdv = sqrtf(var);

    float* ob = out + (size_t)b * 5 * DDIM;
    ob[0 * DDIM + d] = mean;
    ob[1 * DDIM + d] = mx;
    ob[2 * DDIM + d] = mn;
    ob[3 * DDIM + d] = sum;
    ob[4 * DDIM + d] = stdv;
}

extern "C" void kernel_launch(void* const* d_in, const int* in_sizes, int n_in,
                              void* d_out, int out_size, void* d_ws, size_t ws_size,
                              hipStream_t stream) {
    const float* in = (const float*)d_in[0];
    float* out = (float*)d_out;
    float* ws = (float*)d_ws;

    const int nblocks2 = (BATCH * DDIM + 255) / 256;

    // ws need: B * NCHUNK * 4 * 128 floats. NCHUNK=32 -> 4 MB.
    if (ws_size >= (size_t)BATCH * 32 * 4 * DDIM * sizeof(float)) {
        agg_stage1<32><<<BATCH * 32, 256, 0, stream>>>(in, ws);
        agg_stage2<32><<<nblocks2, 256, 0, stream>>>(ws, out);
    } else if (ws_size >= (size_t)BATCH * 8 * 4 * DDIM * sizeof(float)) {
        agg_stage1<8><<<BATCH * 8, 256, 0, stream>>>(in, ws);
        agg_stage2<8><<<nblocks2, 256, 0, stream>>>(ws, out);
    } else {
        agg_stage1<1><<<BATCH, 256, 0, stream>>>(in, ws);
        agg_stage2<1><<<nblocks2, 256, 0, stream>>>(ws, out);
    }
}

// Round 8
// 48.269 us; speedup vs baseline: 4.3527x; 1.0687x over previous
//
#include <hip/hip_runtime.h>
#include <math.h>

#define NROWS 8192
#define DDIM  128
#define BATCH 64

typedef float f4_t __attribute__((ext_vector_type(4)));

__device__ __forceinline__ void f4_add(f4_t& a, const f4_t b) { a += b; }
__device__ __forceinline__ void f4_fma_sq(f4_t& a, const f4_t b) {
    a.x = fmaf(b.x, b.x, a.x); a.y = fmaf(b.y, b.y, a.y);
    a.z = fmaf(b.z, b.z, a.z); a.w = fmaf(b.w, b.w, a.w);
}
__device__ __forceinline__ void f4_max(f4_t& a, const f4_t b) {
    a.x = fmaxf(a.x, b.x); a.y = fmaxf(a.y, b.y);
    a.z = fmaxf(a.z, b.z); a.w = fmaxf(a.w, b.w);
}
__device__ __forceinline__ void f4_min(f4_t& a, const f4_t b) {
    a.x = fminf(a.x, b.x); a.y = fminf(a.y, b.y);
    a.z = fminf(a.z, b.z); a.w = fminf(a.w, b.w);
}

// Stage 1 (R3/R7 proven layout): block (b, c) reduces rows
// {c + j*NCHUNK : j=0..ROWS-1} of batch b — row-interleaved so the NCHUNK
// blocks of a batch sweep one dense 128KB/iter window.
// SINGLE-VARIABLE TEST vs R7: plain loads instead of nontemporal (probing
// whether nt's evict-first marking is what gives the stable ~50% L3
// residency seen in R6's FETCH_SIZE=133MB, or whether plain retains more).
// ws layout: float ws[B][NCHUNK][4][128]  (stat: 0=sum, 1=sumsq, 2=max, 3=min)
template <int NCHUNK>
__global__ __launch_bounds__(256) void agg_stage1(const float* __restrict__ in,
                                                  float* __restrict__ ws) {
    constexpr int ROWS = NROWS / NCHUNK;   // rows per block (256 for NCHUNK=32)
    const int blk = blockIdx.x;
    const int b = blk / NCHUNK;
    const int c = blk % NCHUNK;
    const int tid = threadIdx.x;
    const int d4 = tid & 31;               // float4 column (d = 4*d4..4*d4+3)
    const int rg = tid >> 5;               // row group 0..7

    // row r(j) = c + j*NCHUNK, j = rg + 8*i
    const f4_t* __restrict__ base =
        (const f4_t*)(in + (size_t)b * NROWS * DDIM) +
        (size_t)(c + rg * NCHUNK) * (DDIM / 4) + d4;
    constexpr size_t ISTRIDE = (size_t)8 * NCHUNK * (DDIM / 4); // j += 8

    f4_t sum0 = (f4_t)0.f, sum1 = (f4_t)0.f;
    f4_t sq0  = (f4_t)0.f, sq1  = (f4_t)0.f;
    f4_t mx0  = (f4_t)(-INFINITY), mx1 = (f4_t)(-INFINITY);
    f4_t mn0  = (f4_t)( INFINITY), mn1 = (f4_t)( INFINITY);

    constexpr int ITERS = ROWS / 8;        // 32 for NCHUNK=32
#pragma unroll 8
    for (int i = 0; i < ITERS; i += 2) {
        f4_t v0 = base[(size_t)i * ISTRIDE];
        f4_t v1 = base[(size_t)(i + 1) * ISTRIDE];
        f4_add(sum0, v0); f4_fma_sq(sq0, v0); f4_max(mx0, v0); f4_min(mn0, v0);
        f4_add(sum1, v1); f4_fma_sq(sq1, v1); f4_max(mx1, v1); f4_min(mn1, v1);
    }
    f4_add(sum0, sum1);
    f4_add(sq0, sq1);
    f4_max(mx0, mx1);
    f4_min(mn0, mn1);

    __shared__ f4_t s_sum[256];
    __shared__ f4_t s_sq[256];
    __shared__ f4_t s_mx[256];
    __shared__ f4_t s_mn[256];
    s_sum[tid] = sum0; s_sq[tid] = sq0; s_mx[tid] = mx0; s_mn[tid] = mn0;
    __syncthreads();

    if (tid < 32) {
#pragma unroll
        for (int r = 1; r < 8; ++r) {
            const int i = r * 32 + tid;
            f4_add(sum0, s_sum[i]);
            f4_add(sq0,  s_sq[i]);
            f4_max(mx0,  s_mx[i]);
            f4_min(mn0,  s_mn[i]);
        }
        float* wsb = ws + ((size_t)(b * NCHUNK + c) * 4) * DDIM;
        ((f4_t*)(wsb + 0 * DDIM))[tid] = sum0;
        ((f4_t*)(wsb + 1 * DDIM))[tid] = sq0;
        ((f4_t*)(wsb + 2 * DDIM))[tid] = mx0;
        ((f4_t*)(wsb + 3 * DDIM))[tid] = mn0;
    }
}

// Stage 2: one thread per (b, d); combine NCHUNK partials (fully unrolled),
// emit 5 outputs.
template <int NCHUNK>
__global__ __launch_bounds__(256) void agg_stage2(const float* __restrict__ ws,
                                                  float* __restrict__ out) {
    const int g = blockIdx.x * blockDim.x + threadIdx.x;
    if (g >= BATCH * DDIM) return;
    const int b = g >> 7;
    const int d = g & 127;

    float sum = 0.f, sq = 0.f;
    float mx = -INFINITY, mn = INFINITY;
    const float* pb = ws + (size_t)b * NCHUNK * 4 * DDIM + d;
#pragma unroll
    for (int c = 0; c < NCHUNK; ++c) {
        const float* p = pb + (size_t)c * 4 * DDIM;
        sum += p[0 * DDIM];
        sq  += p[1 * DDIM];
        mx = fmaxf(mx, p[2 * DDIM]);
        mn = fminf(mn, p[3 * DDIM]);
    }
    const float inv_n = 1.f / (float)NROWS;
    const float mean = sum * inv_n;
    const float var = fmaxf(0.f, sq * inv_n - mean * mean);
    const float stdv = sqrtf(var);

    float* ob = out + (size_t)b * 5 * DDIM;
    ob[0 * DDIM + d] = mean;
    ob[1 * DDIM + d] = mx;
    ob[2 * DDIM + d] = mn;
    ob[3 * DDIM + d] = sum;
    ob[4 * DDIM + d] = stdv;
}

extern "C" void kernel_launch(void* const* d_in, const int* in_sizes, int n_in,
                              void* d_out, int out_size, void* d_ws, size_t ws_size,
                              hipStream_t stream) {
    const float* in = (const float*)d_in[0];
    float* out = (float*)d_out;
    float* ws = (float*)d_ws;

    const int nblocks2 = (BATCH * DDIM + 255) / 256;

    // ws need: B * NCHUNK * 4 * 128 floats. NCHUNK=32 -> 4 MB.
    if (ws_size >= (size_t)BATCH * 32 * 4 * DDIM * sizeof(float)) {
        agg_stage1<32><<<BATCH * 32, 256, 0, stream>>>(in, ws);
        agg_stage2<32><<<nblocks2, 256, 0, stream>>>(ws, out);
    } else if (ws_size >= (size_t)BATCH * 8 * 4 * DDIM * sizeof(float)) {
        agg_stage1<8><<<BATCH * 8, 256, 0, stream>>>(in, ws);
        agg_stage2<8><<<nblocks2, 256, 0, stream>>>(ws, out);
    } else {
        agg_stage1<1><<<BATCH, 256, 0, stream>>>(in, ws);
        agg_stage2<1><<<nblocks2, 256, 0, stream>>>(ws, out);
    }
}